// Round 1
// baseline (9917.780 us; speedup 1.0000x reference)
//
#include <hip/hip_runtime.h>
#include <cstddef>
#include <cstdint>

// CubicRNN MI355X — round 5: single-f16 activations (weights were already
// single-f16; measured absmax 3.7e-9 leaves ~1000x headroom), halving MFMA
// work, K-loop LDS traffic, and cat-buffer size. Region 8x8 -> 4x8 so the
// grid is 512 blocks with LDS 46,208 B and <=128 unified regs
// (__launch_bounds__(512,4)) => 2 blocks/CU co-resident: one block's K-loop
// MFMAs hide the other's halo staging + reduce/gating serialization.
// B=4, T=10, C=1, H=W=64, HC=32, S=3, L=3, kx=3, kz=5, ky=1, 18 steps.

typedef __attribute__((ext_vector_type(8))) _Float16 f16x8;
typedef __attribute__((ext_vector_type(4))) float f32x4;
typedef unsigned short u16;

#define HW 4096
#define NB 4

__device__ __forceinline__ float sigm(float x){ return 1.f/(1.f+expf(-x)); }
__device__ __forceinline__ u16 f2h(float x){
  _Float16 h = (_Float16)x;
  union { _Float16 f; u16 u; } c; c.f = h; return c.u;
}

__global__ __launch_bounds__(256) void zero4(uint4* __restrict__ p, size_t n){
  size_t i = (size_t)blockIdx.x*blockDim.x + threadIdx.x;
  size_t st = (size_t)gridDim.x*blockDim.x;
  uint4 z = make_uint4(0u,0u,0u,0u);
  for (; i < n; i += st) p[i] = z;
}

// Pack conv weights (fp32 OIHW) -> [unit=tap*3+kc][co(128)][k(32)] f16 single,
// cat channels remapped to uniform 96 (layer0: ci0->k0, ci1..64->k32..95).
__global__ __launch_bounds__(256) void pack_w(const float* __restrict__ src,
    u16* __restrict__ dst, int taps, int cin, int l0){
  int idx = blockIdx.x*256 + threadIdx.x;
  int k = idx & 31, co = (idx>>5) & 127, rest = idx >> 12;
  int tap = rest/3, kc = rest - tap*3;
  int p = kc*32 + k;
  int ci = l0 ? ((p==0) ? 0 : ((p>=32) ? p-31 : -1)) : p;
  float wv = 0.f;
  if (ci >= 0 && ci < cin) wv = src[((size_t)co*cin + ci)*taps + tap];
  dst[idx] = f2h(wv);
}

// cat layout: [b][chunk 0..11][pixel 0..4095][elem 0..7] f16 single.
// chunk = slot>>3, elem = slot&7 (slot = logical channel 0..95).
__device__ __forceinline__ void put_one(u16* base, int b, int slot, int pix, float v){
  size_t o = ((size_t)(b*12 + (slot>>3))*4096 + pix)*8 + (slot&7);
  base[o] = f2h(v);
}

// Write frame (or fed-back pred) into slot 0 of layer-0 cat bufs.
__global__ __launch_bounds__(256) void frame_fill(const float* __restrict__ inseq,
    const float* __restrict__ predbuf, int step,
    u16* __restrict__ c0, u16* __restrict__ c1, u16* __restrict__ c2){
  int s = blockIdx.y;
  u16* dst = (s==0) ? c0 : ((s==1) ? c1 : c2);
  int i = blockIdx.x*256 + threadIdx.x;          // b*4096 + px
  int b = i >> 12, px = i & 4095;
  int j = step + s;
  float v = (j < 10) ? inseq[((size_t)b*10 + j)*HW + px]
                     : predbuf[(size_t)(j-3)*(NB*HW) + (size_t)b*HW + px];
  put_one(dst, b, 0, px, v);
}

struct CellArgs {
  const u16* cat_in;                       // chunk-planar f16 (12 chunks)
  const u16* wz; const u16* wx;            // packed f16 weights
  const float *bx, *bz;                    // [128]
  const float* cx_src; float* cx_dst;      // [B][4096][32] fp32 (dst may be null)
  float* cz;                               // in-place
  u16 *hx0, *hx1, *hz, *y_dst;             // cat base pointers (null = skip)
  const float *wy, *by;                    // [32][64],[32]
  const float *wl;                         // [32]; non-null = pred mode
  float *pred_out;                         // predbuf slot [B][4096]
  float *final_out;                        // d_out + ti*4096 (b-stride 40960) or null
};

// LDS: [0,18624) halo (12 planes x 97 uint4, 8 rows x 12 cols each);
// overlay after K-loop: exch f32x4 [0,32768); hbuf f32 [32768,41472) [32px][68];
// ybuf f32 [41472,46208) [32px][37].  2 blocks/CU (92,416 B total).
#define LDS_BYTES 46208

__global__ __launch_bounds__(512, 4) void cell_kernel(CellArgs a){
  __shared__ __align__(16) char smem[LDS_BYTES];
  uint4* AU4   = (uint4*)smem;
  f32x4* exch  = (f32x4*)smem;             // 2048 entries = 32 KB
  float* hbufF = (float*)(smem + 32768);
  float* ybufF = (float*)(smem + 41472);

  const int tid = threadIdx.x;
  const int b = blockIdx.y;
  const int reg = blockIdx.x;              // 16 row-bands x 8 col-bands
  const int R0 = (reg >> 3) << 2, C0 = (reg & 7) << 3;   // 4x8 pixel region

  // ---- phase 0: stage 8x12 halo, 12 chunk-planes, coalesced ----
  for (int i = tid; i < 1152; i += 512) {
    int cp = i / 96, px = i - cp*96;
    int hr = px / 12, hc = px - hr*12;
    int gy = R0 + hr - 2, gx = C0 + hc - 2;
    uint4 v = make_uint4(0u,0u,0u,0u);
    if (gy >= 0 && gy < 64 && gx >= 0 && gx < 64)
      v = *reinterpret_cast<const uint4*>(a.cat_in + ((size_t)(b*12 + cp)*4096 + gy*64 + gx)*8);
    AU4[cp*97 + hr*12 + hc] = v;
  }
  __syncthreads();

  // ---- phase 1: K-loop, Ng=2 (64 co/wave) x Kg=4, single-f16 ----
  const int wave = tid >> 6, lane = tid & 63;
  const int n = wave & 1, kg = wave >> 1;
  const int q = lane >> 4, n16 = lane & 15;
  const int row_in = n16 >> 3, col = n16 & 7;
  const int cb = n*64;
  const int wlo = (cb + n16)*32 + q*8;     // lane weight offset (nf adds 512)

  f32x4 zf = {0.f,0.f,0.f,0.f};
  f32x4 accz[4][2], accx[4][2];            // [nf][m]
#pragma unroll
  for (int nf = 0; nf < 4; ++nf)
#pragma unroll
    for (int m = 0; m < 2; ++m) { accz[nf][m] = zf; accx[nf][m] = zf; }

#pragma unroll 1
  for (int u = kg; u < 75; u += 4) {
    int tap = u/3, kc = u - tap*3;
    int ky = tap/5, kx = tap - ky*5;
    bool inner = ((unsigned)(ky-1) <= 2u) && ((unsigned)(kx-1) <= 2u);

    f16x8 Bz[4];
#pragma unroll
    for (int nf = 0; nf < 4; ++nf)
      Bz[nf] = *(const f16x8*)(a.wz + (size_t)u*4096 + wlo + nf*512);

    f16x8 Bx[4];
    if (inner) {
      int xu = ((ky-1)*3 + (kx-1))*3 + kc;
#pragma unroll
      for (int nf = 0; nf < 4; ++nf)
        Bx[nf] = *(const f16x8*)(a.wx + (size_t)xu*4096 + wlo + nf*512);
    }

    int ai0 = (kc*4 + q)*97 + (row_in + ky)*12 + col + kx;
    f16x8 Ah[2];
#pragma unroll
    for (int m = 0; m < 2; ++m)
      Ah[m] = *(const f16x8*)(AU4 + ai0 + m*24);

    __builtin_amdgcn_s_setprio(1);
#pragma unroll
    for (int nf = 0; nf < 4; ++nf)
#pragma unroll
      for (int m = 0; m < 2; ++m)
        accz[nf][m] = __builtin_amdgcn_mfma_f32_16x16x32_f16(Ah[m], Bz[nf], accz[nf][m], 0,0,0);
    if (inner) {
#pragma unroll
      for (int nf = 0; nf < 4; ++nf)
#pragma unroll
        for (int m = 0; m < 2; ++m)
          accx[nf][m] = __builtin_amdgcn_mfma_f32_16x16x32_f16(Ah[m], Bx[nf], accx[nf][m], 0,0,0);
    }
    __builtin_amdgcn_s_setprio(0);
  }

  // ---- phase 2: K-reduce (4-way) fused with gating, 4 passes ----
#pragma unroll 1
  for (int pass = 0; pass < 4; ++pass) {
    const int br = pass >> 1, mh = pass & 1;       // br0=z, br1=x; m-frag mh
    __syncthreads();                               // exch free (halo dead / prev pass read)
#pragma unroll
    for (int nf = 0; nf < 4; ++nf)
      exch[(((kg*2 + n)*4 + nf)*64) + lane] = br ? accx[nf][mh] : accz[nf][mh];
    __syncthreads();
    if (tid < 128) {
      int ch = tid & 31, qq = tid >> 5;            // 4 px-quads x 32 channels
      const float* bias = br ? a.bx : a.bz;
      float gsum[4][4];                            // [gate][r]
#pragma unroll
      for (int g = 0; g < 4; ++g) {
        int co = g*32 + ch;
        int nn = co >> 6, nf = (co >> 4) & 3, nl = co & 15;
        f32x4 s = zf;
#pragma unroll
        for (int kgg = 0; kgg < 4; ++kgg)
          s += exch[(((kgg*2 + nn)*4 + nf)*64) + qq*16 + nl];
        float bb = bias[co];
#pragma unroll
        for (int r = 0; r < 4; ++r) gsum[g][r] = s[r] + bb;
      }
#pragma unroll
      for (int r = 0; r < 4; ++r) {
        int p16 = qq*4 + r;
        int row = 2*mh + (p16 >> 3), cc = p16 & 7;
        int pxl = row*8 + cc;                      // 0..31 local pixel
        int pxg = (R0 + row)*64 + C0 + cc;
        size_t pix = (size_t)b*4096 + pxg;
        float ig = gsum[0][r], fg = gsum[1][r], gg = gsum[2][r], og = gsum[3][r];
        if (br == 0) {                             // z-branch
          float c = a.cz[pix*32 + ch];
          float cn = sigm(fg + 0.01f)*c + sigm(ig)*tanhf(gg);
          float h = sigm(og)*tanhf(cn);
          a.cz[pix*32 + ch] = cn;
          if (a.hz) put_one(a.hz, b, 64 + ch, pxg, h);
          hbufF[pxl*68 + 32 + ch] = h;
        } else {                                   // x-branch
          float c = a.cx_src[pix*32 + ch];
          float cn = sigm(fg + 0.01f)*c + sigm(ig)*tanhf(gg);
          float h = sigm(og)*tanhf(cn);
          if (a.cx_dst) a.cx_dst[pix*32 + ch] = cn;
          if (a.hx0) put_one(a.hx0, b, 32 + ch, pxg, h);
          if (a.hx1) put_one(a.hx1, b, 32 + ch, pxg, h);
          hbufF[pxl*68 + ch] = h;
        }
      }
    }
  }
  __syncthreads();

  // ---- phase 3: fused 1x1 y-conv (64 -> 32) ----
  if (a.wy) {
#pragma unroll 1
    for (int it = 0; it < 2; ++it) {
      int idx = tid + it*512;
      int co2 = idx & 31, pxl = idx >> 5;          // 0..31
      int pxg = (R0 + (pxl >> 3))*64 + C0 + (pxl & 7);
      float acc = a.by[co2];
#pragma unroll
      for (int c2 = 0; c2 < 64; ++c2) acc += a.wy[co2*64 + c2] * hbufF[pxl*68 + c2];
      if (a.y_dst) put_one(a.y_dst, b, co2, pxg, acc);
      if (a.wl) ybufF[pxl*37 + co2] = acc;
    }
  }
  // ---- phase 4: fused pred-conv (32 -> 1), last cell only ----
  if (a.wl) {
    __syncthreads();
    if (tid < 32) {
      int pxl = tid;
      int pxg = (R0 + (pxl >> 3))*64 + C0 + (pxl & 7);
      float p = 0.f;
#pragma unroll
      for (int c2 = 0; c2 < 32; ++c2) p += a.wl[c2] * ybufF[pxl*37 + c2];
      a.pred_out[(size_t)b*4096 + pxg] = p;
      if (a.final_out) a.final_out[(size_t)b*40960 + pxg] = p;
    }
  }
}

extern "C" void kernel_launch(void* const* d_in, const int* in_sizes, int n_in,
                              void* d_out, int out_size, void* d_ws, size_t ws_size,
                              hipStream_t stream)
{
  const float* input_seq = (const float*)d_in[0];
  const float* w_x0 = (const float*)d_in[1];
  const float* b_x0 = (const float*)d_in[2];
  const float* w_z0 = (const float*)d_in[3];
  const float* b_z0 = (const float*)d_in[4];
  const float* w_y0 = (const float*)d_in[5];
  const float* b_y0 = (const float*)d_in[6];
  const float* w_x1 = (const float*)d_in[7];
  const float* b_x1 = (const float*)d_in[8];
  const float* w_z1 = (const float*)d_in[9];
  const float* b_z1 = (const float*)d_in[10];
  const float* w_y1 = (const float*)d_in[11];
  const float* b_y1 = (const float*)d_in[12];
  const float* w_last = (const float*)d_in[13];
  (void)in_sizes; (void)n_in; (void)out_size; (void)ws_size;

  uint8_t* wsb = (uint8_t*)d_ws;
  size_t off = 0;
  auto alloc = [&](size_t bytes) -> void* {
    void* p = wsb + off; off += (bytes + 255) & ~(size_t)255; return p;
  };

  const size_t CATB = (size_t)NB*12*4096*8*2;    // 3,145,728 B (chunk-planar f16)
  u16* cat[3][3][2];
  for (int l = 0; l < 3; ++l)
    for (int s = 0; s < 3; ++s) {
      cat[l][s][0] = (u16*)alloc(CATB);
      cat[l][s][1] = (s == 0) ? (u16*)alloc(CATB) : cat[l][s][0];
    }
  const size_t CB = (size_t)NB*HW*32*4;          // 2,097,152 B
  float* cx[3][2]; float* cz[3];
  for (int l = 0; l < 3; ++l) { cx[l][0] = (float*)alloc(CB); cx[l][1] = (float*)alloc(CB); }
  for (int l = 0; l < 3; ++l) cz[l] = (float*)alloc(CB);
  size_t zero_bytes = off;                       // cats + cx + cz

  u16 *wzb[9], *wxb[9];
  for (int c = 0; c < 9; ++c) {
    wzb[c] = (u16*)alloc(75*4096*2);             // 25 taps x 3 kc x 128 co x 32 k
    wxb[c] = (u16*)alloc(27*4096*2);             // 9 taps x 3 kc
  }
  float* predbuf = (float*)alloc((size_t)18*NB*HW*4);

  zero4<<<2048, 256, 0, stream>>>((uint4*)wsb, zero_bytes/16);

  for (int l = 0; l < 3; ++l)
    for (int s = 0; s < 3; ++s) {
      int cell = l*3 + s;
      const float *srcx, *srcz; int cin;
      if (l == 0) { srcx = w_x0 + (size_t)s*128*65*9;  srcz = w_z0 + (size_t)s*128*65*25;  cin = 65; }
      else { int li = (l-1)*3 + s;
             srcx = w_x1 + (size_t)li*128*96*9; srcz = w_z1 + (size_t)li*128*96*25; cin = 96; }
      pack_w<<<(75*4096)/256, 256, 0, stream>>>(srcz, wzb[cell], 25, cin, l==0);
      pack_w<<<(27*4096)/256, 256, 0, stream>>>(srcx, wxb[cell], 9, cin, l==0);
    }

  for (int step = 0; step < 18; ++step) {
    int par = step & 1, npar = par ^ 1;
    frame_fill<<<dim3(64,3), 256, 0, stream>>>(input_seq, predbuf, step,
        cat[0][0][par], cat[0][1][0], cat[0][2][0]);
    for (int l = 0; l < 3; ++l)
      for (int s = 0; s < 3; ++s) {
        int cell = l*3 + s;
        CellArgs A;
        A.cat_in = cat[l][s][(s==0) ? par : 0];
        A.wz = wzb[cell]; A.wx = wxb[cell];
        if (l == 0) { A.bx = b_x0 + s*128; A.bz = b_z0 + s*128; }
        else { int li = (l-1)*3 + s; A.bx = b_x1 + li*128; A.bz = b_z1 + li*128; }
        A.cx_src = (s == 2) ? cx[l][1] : cx[l][0];
        A.cx_dst = (s == 0) ? cx[l][0] : ((s == 1) ? cx[l][1] : nullptr);
        A.cz = cz[l];
        A.hx0 = (s == 0) ? cat[l][1][0] : ((s == 1) ? cat[l][2][0] : nullptr);
        A.hx1 = (s == 0) ? cat[l][0][npar] : nullptr;
        A.hz  = (s < 2) ? cat[l][s+1][0] : cat[l][0][npar];
        A.wy = nullptr; A.by = nullptr; A.y_dst = nullptr;
        A.wl = nullptr; A.pred_out = nullptr; A.final_out = nullptr;
        if (l < 2) {
          if (l == 0) { A.wy = w_y0 + (size_t)s*32*64; A.by = b_y0 + s*32; }
          else        { A.wy = w_y1 + (size_t)s*32*64; A.by = b_y1 + s*32; }
          A.y_dst = cat[l+1][s][(s==0) ? par : 0];
        } else if (s == 2) {
          A.wy = w_y1 + (size_t)5*32*64; A.by = b_y1 + 5*32;
          A.wl = w_last;
          A.pred_out = predbuf + (size_t)step*NB*HW;
          A.final_out = (step >= 8) ? ((float*)d_out + (size_t)(step-8)*HW) : nullptr;
        }
        cell_kernel<<<dim3(128, NB), 512, 0, stream>>>(A);
      }
  }
}

// Round 2
// 8789.286 us; speedup vs baseline: 1.1284x; 1.1284x over previous
//
#include <hip/hip_runtime.h>
#include <cstddef>
#include <cstdint>

// CubicRNN MI355X — round 6: round-4 structure (8x8 regions, 256 blocks,
// 1 block/CU, depth-1 B-prefetch) + the round-5-validated single-f16
// activation axis (absmax bit-identical): 12 chunk planes, 1 ds_read + 1 MFMA
// per logical product, cat buffers halved. Round 5's 4x8/2-block structure
// reverted (L2 thrash: WRITE_SIZE 10->104 MB, dur 42->70 us).
// B=4, T=10, C=1, H=W=64, HC=32, S=3, L=3, kx=3, kz=5, ky=1, 18 steps.

typedef __attribute__((ext_vector_type(8))) _Float16 f16x8;
typedef __attribute__((ext_vector_type(4))) float f32x4;
typedef unsigned short u16;

#define HW 4096
#define NB 4

__device__ __forceinline__ float sigm(float x){ return 1.f/(1.f+expf(-x)); }
__device__ __forceinline__ u16 f2h(float x){
  _Float16 h = (_Float16)x;
  union { _Float16 f; u16 u; } c; c.f = h; return c.u;
}

__global__ __launch_bounds__(256) void zero4(uint4* __restrict__ p, size_t n){
  size_t i = (size_t)blockIdx.x*blockDim.x + threadIdx.x;
  size_t st = (size_t)gridDim.x*blockDim.x;
  uint4 z = make_uint4(0u,0u,0u,0u);
  for (; i < n; i += st) p[i] = z;
}

// Pack conv weights (fp32 OIHW) -> [unit=tap*3+kc][co(128)][k(32)] f16 single,
// cat channels remapped to uniform 96 (layer0: ci0->k0, ci1..64->k32..95).
__global__ __launch_bounds__(256) void pack_w(const float* __restrict__ src,
    u16* __restrict__ dst, int taps, int cin, int l0){
  int idx = blockIdx.x*256 + threadIdx.x;
  int k = idx & 31, co = (idx>>5) & 127, rest = idx >> 12;
  int tap = rest/3, kc = rest - tap*3;
  int p = kc*32 + k;
  int ci = l0 ? ((p==0) ? 0 : ((p>=32) ? p-31 : -1)) : p;
  float wv = 0.f;
  if (ci >= 0 && ci < cin) wv = src[((size_t)co*cin + ci)*taps + tap];
  dst[idx] = f2h(wv);
}

// cat layout: [b][chunk 0..11][pixel 0..4095][elem 0..7] f16 single.
// chunk = slot>>3, elem = slot&7 (slot = logical channel 0..95).
__device__ __forceinline__ void put_one(u16* base, int b, int slot, int pix, float v){
  size_t o = ((size_t)(b*12 + (slot>>3))*4096 + pix)*8 + (slot&7);
  base[o] = f2h(v);
}

// Write frame (or fed-back pred) into slot 0 of layer-0 cat bufs.
__global__ __launch_bounds__(256) void frame_fill(const float* __restrict__ inseq,
    const float* __restrict__ predbuf, int step,
    u16* __restrict__ c0, u16* __restrict__ c1, u16* __restrict__ c2){
  int s = blockIdx.y;
  u16* dst = (s==0) ? c0 : ((s==1) ? c1 : c2);
  int i = blockIdx.x*256 + threadIdx.x;          // b*4096 + px
  int b = i >> 12, px = i & 4095;
  int j = step + s;
  float v = (j < 10) ? inseq[((size_t)b*10 + j)*HW + px]
                     : predbuf[(size_t)(j-3)*(NB*HW) + (size_t)b*HW + px];
  put_one(dst, b, 0, px, v);
}

struct CellArgs {
  const u16* cat_in;                       // chunk-planar f16 (12 chunks)
  const u16* wz; const u16* wx;            // packed f16 weights
  const float *bx, *bz;                    // [128]
  const float* cx_src; float* cx_dst;      // [B][4096][32] fp32 (dst may be null)
  float* cz;                               // in-place
  u16 *hx0, *hx1, *hz, *y_dst;             // cat base pointers (null = skip)
  const float *wy, *by;                    // [32][64],[32]
  const float *wl;                         // [32]; non-null = pred mode
  float *pred_out;                         // predbuf slot [B][4096]
  float *final_out;                        // d_out + ti*4096 (b-stride 40960) or null
};

// LDS: [0,27840) halo (12 chunk-planes x 145 uint4, 12x12 each); overlay after
// K-loop: exch f32x4 [0,65536) ; hbuf f32 [65536, 82944) [64px][68] ;
//   ybuf f32 [82944, 92416) [64px][37]
#define LDS_BYTES 92416

__global__ __launch_bounds__(512, 2) void cell_kernel(CellArgs a){
  __shared__ __align__(16) char smem[LDS_BYTES];
  uint4* AU4   = (uint4*)smem;
  f32x4* exch  = (f32x4*)smem;             // 4096 entries = 64 KB
  float* hbufF = (float*)(smem + 65536);
  float* ybufF = (float*)(smem + 82944);

  const int tid = threadIdx.x;
  const int b = blockIdx.y;
  const int reg = blockIdx.x;
  const int R0 = (reg >> 3) << 3, C0 = (reg & 7) << 3;   // 8x8 pixel region

  // ---- phase 0: stage 12x12 halo, 12 chunk-planes, coalesced ----
  for (int i = tid; i < 1728; i += 512) {
    int cp = i / 144, px = i - cp*144;
    int hr = px / 12, hc = px - hr*12;
    int gy = R0 + hr - 2, gx = C0 + hc - 2;
    uint4 v = make_uint4(0u,0u,0u,0u);
    if (gy >= 0 && gy < 64 && gx >= 0 && gx < 64)
      v = *reinterpret_cast<const uint4*>(a.cat_in + ((size_t)(b*12 + cp)*4096 + gy*64 + gx)*8);
    AU4[cp*145 + px] = v;
  }
  __syncthreads();

  // ---- phase 1: K-loop, Ng=2 (64 co/wave) x Kg=4, single-f16 ----
  const int wave = tid >> 6, lane = tid & 63;
  const int n = wave & 1, kg = wave >> 1;
  const int q = lane >> 4, n16 = lane & 15;
  const int row_in = n16 >> 3, col = n16 & 7;
  const int cb = n*64;
  const int wlo = (cb + n16)*32 + q*8;     // lane weight offset (nf adds 512)

  f32x4 zf = {0.f,0.f,0.f,0.f};
  f32x4 accz[4][4], accx[4][4];            // [nf][m]
#pragma unroll
  for (int nf = 0; nf < 4; ++nf)
#pragma unroll
    for (int m = 0; m < 4; ++m) { accz[nf][m] = zf; accx[nf][m] = zf; }

  f16x8 Bz[4];
#pragma unroll
  for (int nf = 0; nf < 4; ++nf)
    Bz[nf] = *(const f16x8*)(a.wz + (size_t)kg*4096 + wlo + nf*512);

#pragma unroll 1
  for (int u = kg; u < 75; u += 4) {
    int tap = u/3, kc = u - tap*3;
    int ky = tap/5, kx = tap - ky*5;
    bool inner = ((unsigned)(ky-1) <= 2u) && ((unsigned)(kx-1) <= 2u);

    f16x8 Bx[4];
    if (inner) {
      int xu = ((ky-1)*3 + (kx-1))*3 + kc;
#pragma unroll
      for (int nf = 0; nf < 4; ++nf)
        Bx[nf] = *(const f16x8*)(a.wx + (size_t)xu*4096 + wlo + nf*512);
    }

    int ai0 = (kc*4 + q)*145 + (row_in + ky)*12 + col + kx;
    f16x8 Ah[4];
#pragma unroll
    for (int m = 0; m < 4; ++m)
      Ah[m] = *(const f16x8*)(AU4 + ai0 + m*24);

#pragma unroll
    for (int nf = 0; nf < 4; ++nf)
#pragma unroll
      for (int m = 0; m < 4; ++m)
        accz[nf][m] = __builtin_amdgcn_mfma_f32_16x16x32_f16(Ah[m], Bz[nf], accz[nf][m], 0,0,0);

    // prefetch next z-B (depth-1, hides L2 latency)
    int un = (u + 4 < 75) ? u + 4 : kg;
    f16x8 Bzn[4];
#pragma unroll
    for (int nf = 0; nf < 4; ++nf)
      Bzn[nf] = *(const f16x8*)(a.wz + (size_t)un*4096 + wlo + nf*512);

    if (inner) {
#pragma unroll
      for (int nf = 0; nf < 4; ++nf)
#pragma unroll
        for (int m = 0; m < 4; ++m)
          accx[nf][m] = __builtin_amdgcn_mfma_f32_16x16x32_f16(Ah[m], Bx[nf], accx[nf][m], 0,0,0);
    }
#pragma unroll
    for (int nf = 0; nf < 4; ++nf) Bz[nf] = Bzn[nf];
  }

  // ---- phase 2: K-reduce (4-way) fused with gating, 4 passes ----
#pragma unroll 1
  for (int pass = 0; pass < 4; ++pass) {
    const int br = pass >> 1, mh = pass & 1;       // br0=z, br1=x; Mfrags {2mh,2mh+1}
    __syncthreads();                               // exch free (halo dead / prev pass read)
#pragma unroll
    for (int nf = 0; nf < 4; ++nf)
#pragma unroll
      for (int ml = 0; ml < 2; ++ml) {
        int m = mh*2 + ml;
        exch[((((kg*2 + n)*4 + nf)*2 + ml)*64) + lane] = br ? accx[nf][m] : accz[nf][m];
      }
    __syncthreads();
    if (tid < 256) {
      int ch = tid & 31, pxq = tid >> 5;           // 8 px-quads x 32 channels
      int ml = pxq >> 2, qq = pxq & 3;
      const float* bias = br ? a.bx : a.bz;
      float gsum[4][4];                            // [gate][r]
#pragma unroll
      for (int g = 0; g < 4; ++g) {
        int co = g*32 + ch;
        int nn = co >> 6, nf = (co >> 4) & 3, nl = co & 15;
        int li = qq*16 + nl;
        f32x4 s = zf;
#pragma unroll
        for (int kgg = 0; kgg < 4; ++kgg)
          s += exch[((((kgg*2 + nn)*4 + nf)*2 + ml)*64) + li];
        float bb = bias[co];
#pragma unroll
        for (int r = 0; r < 4; ++r) gsum[g][r] = s[r] + bb;
      }
#pragma unroll
      for (int r = 0; r < 4; ++r) {
        int p16 = qq*4 + r;
        int m = mh*2 + ml;
        int px = (2*m + (p16 >> 3))*8 + (p16 & 7);
        int pxg = (R0 + (px >> 3))*64 + C0 + (px & 7);
        size_t pix = (size_t)b*4096 + pxg;
        float ig = gsum[0][r], fg = gsum[1][r], gg = gsum[2][r], og = gsum[3][r];
        if (br == 0) {                             // z-branch
          float c = a.cz[pix*32 + ch];
          float cn = sigm(fg + 0.01f)*c + sigm(ig)*tanhf(gg);
          float h = sigm(og)*tanhf(cn);
          a.cz[pix*32 + ch] = cn;
          if (a.hz) put_one(a.hz, b, 64 + ch, pxg, h);
          hbufF[px*68 + 32 + ch] = h;
        } else {                                   // x-branch
          float c = a.cx_src[pix*32 + ch];
          float cn = sigm(fg + 0.01f)*c + sigm(ig)*tanhf(gg);
          float h = sigm(og)*tanhf(cn);
          if (a.cx_dst) a.cx_dst[pix*32 + ch] = cn;
          if (a.hx0) put_one(a.hx0, b, 32 + ch, pxg, h);
          if (a.hx1) put_one(a.hx1, b, 32 + ch, pxg, h);
          hbufF[px*68 + ch] = h;
        }
      }
    }
  }
  __syncthreads();

  // ---- phase 3: fused 1x1 y-conv (64 -> 32) ----
  if (a.wy) {
#pragma unroll 1
    for (int it = 0; it < 4; ++it) {
      int idx = tid + it*512;
      int co2 = idx & 31, px = idx >> 5;
      int pxg = (R0 + (px >> 3))*64 + C0 + (px & 7);
      float acc = a.by[co2];
#pragma unroll
      for (int c2 = 0; c2 < 64; ++c2) acc += a.wy[co2*64 + c2] * hbufF[px*68 + c2];
      if (a.y_dst) put_one(a.y_dst, b, co2, pxg, acc);
      if (a.wl) ybufF[px*37 + co2] = acc;
    }
  }
  // ---- phase 4: fused pred-conv (32 -> 1), last cell only ----
  if (a.wl) {
    __syncthreads();
    if (tid < 64) {
      int px = tid;
      int pxg = (R0 + (px >> 3))*64 + C0 + (px & 7);
      float p = 0.f;
#pragma unroll
      for (int c2 = 0; c2 < 32; ++c2) p += a.wl[c2] * ybufF[px*37 + c2];
      a.pred_out[(size_t)b*4096 + pxg] = p;
      if (a.final_out) a.final_out[(size_t)b*40960 + pxg] = p;
    }
  }
}

extern "C" void kernel_launch(void* const* d_in, const int* in_sizes, int n_in,
                              void* d_out, int out_size, void* d_ws, size_t ws_size,
                              hipStream_t stream)
{
  const float* input_seq = (const float*)d_in[0];
  const float* w_x0 = (const float*)d_in[1];
  const float* b_x0 = (const float*)d_in[2];
  const float* w_z0 = (const float*)d_in[3];
  const float* b_z0 = (const float*)d_in[4];
  const float* w_y0 = (const float*)d_in[5];
  const float* b_y0 = (const float*)d_in[6];
  const float* w_x1 = (const float*)d_in[7];
  const float* b_x1 = (const float*)d_in[8];
  const float* w_z1 = (const float*)d_in[9];
  const float* b_z1 = (const float*)d_in[10];
  const float* w_y1 = (const float*)d_in[11];
  const float* b_y1 = (const float*)d_in[12];
  const float* w_last = (const float*)d_in[13];
  (void)in_sizes; (void)n_in; (void)out_size; (void)ws_size;

  uint8_t* wsb = (uint8_t*)d_ws;
  size_t off = 0;
  auto alloc = [&](size_t bytes) -> void* {
    void* p = wsb + off; off += (bytes + 255) & ~(size_t)255; return p;
  };

  const size_t CATB = (size_t)NB*12*4096*8*2;    // 3,145,728 B (chunk-planar f16)
  u16* cat[3][3][2];
  for (int l = 0; l < 3; ++l)
    for (int s = 0; s < 3; ++s) {
      cat[l][s][0] = (u16*)alloc(CATB);
      cat[l][s][1] = (s == 0) ? (u16*)alloc(CATB) : cat[l][s][0];
    }
  const size_t CB = (size_t)NB*HW*32*4;          // 2,097,152 B
  float* cx[3][2]; float* cz[3];
  for (int l = 0; l < 3; ++l) { cx[l][0] = (float*)alloc(CB); cx[l][1] = (float*)alloc(CB); }
  for (int l = 0; l < 3; ++l) cz[l] = (float*)alloc(CB);
  size_t zero_bytes = off;                       // cats + cx + cz

  u16 *wzb[9], *wxb[9];
  for (int c = 0; c < 9; ++c) {
    wzb[c] = (u16*)alloc(75*4096*2);             // 25 taps x 3 kc x 128 co x 32 k
    wxb[c] = (u16*)alloc(27*4096*2);             // 9 taps x 3 kc
  }
  float* predbuf = (float*)alloc((size_t)18*NB*HW*4);

  zero4<<<2048, 256, 0, stream>>>((uint4*)wsb, zero_bytes/16);

  for (int l = 0; l < 3; ++l)
    for (int s = 0; s < 3; ++s) {
      int cell = l*3 + s;
      const float *srcx, *srcz; int cin;
      if (l == 0) { srcx = w_x0 + (size_t)s*128*65*9;  srcz = w_z0 + (size_t)s*128*65*25;  cin = 65; }
      else { int li = (l-1)*3 + s;
             srcx = w_x1 + (size_t)li*128*96*9; srcz = w_z1 + (size_t)li*128*96*25; cin = 96; }
      pack_w<<<(75*4096)/256, 256, 0, stream>>>(srcz, wzb[cell], 25, cin, l==0);
      pack_w<<<(27*4096)/256, 256, 0, stream>>>(srcx, wxb[cell], 9, cin, l==0);
    }

  for (int step = 0; step < 18; ++step) {
    int par = step & 1, npar = par ^ 1;
    frame_fill<<<dim3(64,3), 256, 0, stream>>>(input_seq, predbuf, step,
        cat[0][0][par], cat[0][1][0], cat[0][2][0]);
    for (int l = 0; l < 3; ++l)
      for (int s = 0; s < 3; ++s) {
        int cell = l*3 + s;
        CellArgs A;
        A.cat_in = cat[l][s][(s==0) ? par : 0];
        A.wz = wzb[cell]; A.wx = wxb[cell];
        if (l == 0) { A.bx = b_x0 + s*128; A.bz = b_z0 + s*128; }
        else { int li = (l-1)*3 + s; A.bx = b_x1 + li*128; A.bz = b_z1 + li*128; }
        A.cx_src = (s == 2) ? cx[l][1] : cx[l][0];
        A.cx_dst = (s == 0) ? cx[l][0] : ((s == 1) ? cx[l][1] : nullptr);
        A.cz = cz[l];
        A.hx0 = (s == 0) ? cat[l][1][0] : ((s == 1) ? cat[l][2][0] : nullptr);
        A.hx1 = (s == 0) ? cat[l][0][npar] : nullptr;
        A.hz  = (s < 2) ? cat[l][s+1][0] : cat[l][0][npar];
        A.wy = nullptr; A.by = nullptr; A.y_dst = nullptr;
        A.wl = nullptr; A.pred_out = nullptr; A.final_out = nullptr;
        if (l < 2) {
          if (l == 0) { A.wy = w_y0 + (size_t)s*32*64; A.by = b_y0 + s*32; }
          else        { A.wy = w_y1 + (size_t)s*32*64; A.by = b_y1 + s*32; }
          A.y_dst = cat[l+1][s][(s==0) ? par : 0];
        } else if (s == 2) {
          A.wy = w_y1 + (size_t)5*32*64; A.by = b_y1 + 5*32;
          A.wl = w_last;
          A.pred_out = predbuf + (size_t)step*NB*HW;
          A.final_out = (step >= 8) ? ((float*)d_out + (size_t)(step-8)*HW) : nullptr;
        }
        cell_kernel<<<dim3(64, NB), 512, 0, stream>>>(A);
      }
  }
}

// Round 3
// 5193.587 us; speedup vs baseline: 1.9096x; 1.6923x over previous
//
#include <hip/hip_runtime.h>
#include <cstddef>
#include <cstdint>

// CubicRNN MI355X — round 7: round-4 kernel with ALL global address streams
// byte-identical (24-chunk cat layout, put_pair dual-plane writes, 6MB CATB,
// 24-plane halo staging), but single-f16 COMPUTE only: the lo-half (Al)
// LDS reads + MFMAs are dropped (numerics proven bit-identical in r5/r6,
// absmax 3.7e-9). Isolates compute-halving from the layout change that
// caused r5/r6's 13-19x EA write amplification (WRITE 10->139 MB).
// B=4, T=10, C=1, H=W=64, HC=32, S=3, L=3, kx=3, kz=5, ky=1, 18 steps.

typedef __attribute__((ext_vector_type(8))) _Float16 f16x8;
typedef __attribute__((ext_vector_type(4))) float f32x4;
typedef unsigned short u16;

#define HW 4096
#define NB 4

__device__ __forceinline__ float sigm(float x){ return 1.f/(1.f+expf(-x)); }
__device__ __forceinline__ u16 f2h(float x){
  _Float16 h = (_Float16)x;
  union { _Float16 f; u16 u; } c; c.f = h; return c.u;
}

__global__ __launch_bounds__(256) void zero4(uint4* __restrict__ p, size_t n){
  size_t i = (size_t)blockIdx.x*blockDim.x + threadIdx.x;
  size_t st = (size_t)gridDim.x*blockDim.x;
  uint4 z = make_uint4(0u,0u,0u,0u);
  for (; i < n; i += st) p[i] = z;
}

// Pack conv weights (fp32 OIHW) -> [unit=tap*3+kc][co(128)][k(32)] f16 single,
// cat channels remapped to uniform 96 (layer0: ci0->k0, ci1..64->k32..95).
__global__ __launch_bounds__(256) void pack_w(const float* __restrict__ src,
    u16* __restrict__ dst, int taps, int cin, int l0){
  int idx = blockIdx.x*256 + threadIdx.x;
  int k = idx & 31, co = (idx>>5) & 127, rest = idx >> 12;
  int tap = rest/3, kc = rest - tap*3;
  int p = kc*32 + k;
  int ci = l0 ? ((p==0) ? 0 : ((p>=32) ? p-31 : -1)) : p;
  float wv = 0.f;
  if (ci >= 0 && ci < cin) wv = src[((size_t)co*cin + ci)*taps + tap];
  dst[idx] = f2h(wv);
}

// cat layout: [b][chunk 0..23][pixel 0..4095][elem 0..7] f16
// chunk = half*12 + (logical_slot>>3); half 0 = hi, 1 = lo; elem = slot&7.
// (lo planes retained write-side to keep the r4-proven address streams;
//  they are no longer consumed by the K-loop.)
__device__ __forceinline__ void put_pair(u16* base, int b, int slot, int pix, float v){
  _Float16 h = (_Float16)v;
  float lof = v - (float)h;
  size_t o = ((size_t)(b*24 + (slot>>3))*4096 + pix)*8 + (slot&7);
  base[o] = f2h(v);
  base[o + (size_t)393216] = f2h(lof);   // +12 chunks
}

// Write frame (or fed-back pred) into slot 0 of layer-0 cat bufs.
__global__ __launch_bounds__(256) void frame_fill(const float* __restrict__ inseq,
    const float* __restrict__ predbuf, int step,
    u16* __restrict__ c0, u16* __restrict__ c1, u16* __restrict__ c2){
  int s = blockIdx.y;
  u16* dst = (s==0) ? c0 : ((s==1) ? c1 : c2);
  int i = blockIdx.x*256 + threadIdx.x;          // b*4096 + px
  int b = i >> 12, px = i & 4095;
  int j = step + s;
  float v = (j < 10) ? inseq[((size_t)b*10 + j)*HW + px]
                     : predbuf[(size_t)(j-3)*(NB*HW) + (size_t)b*HW + px];
  put_pair(dst, b, 0, px, v);
}

struct CellArgs {
  const u16* cat_in;                       // chunk-planar f16 pairs
  const u16* wz; const u16* wx;            // packed f16 weights
  const float *bx, *bz;                    // [128]
  const float* cx_src; float* cx_dst;      // [B][4096][32] fp32 (dst may be null)
  float* cz;                               // in-place
  u16 *hx0, *hx1, *hz, *y_dst;             // cat base pointers (null = skip)
  const float *wy, *by;                    // [32][64],[32]
  const float *wl;                         // [32]; non-null = pred mode
  float *pred_out;                         // predbuf slot [B][4096]
  float *final_out;                        // d_out + ti*4096 (b-stride 40960) or null
};

// LDS: [0,55680) halo (24 chunks x 145 uint4); overlay after K-loop:
//   exch f32x4 [0,65536) ; hbuf f32 [65536, 82944) [64px][68] ;
//   ybuf f32 [82944, 92416) [64px][37]
#define LDS_BYTES 92416

__global__ __launch_bounds__(512, 2) void cell_kernel(CellArgs a){
  __shared__ __align__(16) char smem[LDS_BYTES];
  uint4* AU4   = (uint4*)smem;
  f32x4* exch  = (f32x4*)smem;             // 4096 entries = 64 KB
  float* hbufF = (float*)(smem + 65536);
  float* ybufF = (float*)(smem + 82944);

  const int tid = threadIdx.x;
  const int b = blockIdx.y;
  const int reg = blockIdx.x;
  const int R0 = (reg >> 3) << 3, C0 = (reg & 7) << 3;   // 8x8 pixel region

  // ---- phase 0: stage 12x12 halo, 24 chunk-planes, coalesced (r4-identical) ----
  for (int i = tid; i < 3456; i += 512) {
    int px = i % 144, cp = i / 144;
    int hr = px / 12, hc = px - hr*12;
    int gy = R0 + hr - 2, gx = C0 + hc - 2;
    uint4 v = make_uint4(0u,0u,0u,0u);
    if (gy >= 0 && gy < 64 && gx >= 0 && gx < 64)
      v = *reinterpret_cast<const uint4*>(a.cat_in + ((size_t)(b*24 + cp)*4096 + gy*64 + gx)*8);
    AU4[cp*145 + px] = v;
  }
  __syncthreads();

  // ---- phase 1: K-loop, Ng=2 (64 co/wave) x Kg=4; hi-half MFMAs only ----
  const int wave = tid >> 6, lane = tid & 63;
  const int n = wave & 1, kg = wave >> 1;
  const int q = lane >> 4, n16 = lane & 15;
  const int row_in = n16 >> 3, col = n16 & 7;
  const int cb = n*64;
  const int wlo = (cb + n16)*32 + q*8;     // lane weight offset (nf adds 512)

  f32x4 zf = {0.f,0.f,0.f,0.f};
  f32x4 accz[4][4], accx[4][4];            // [nf][m]
#pragma unroll
  for (int nf = 0; nf < 4; ++nf)
#pragma unroll
    for (int m = 0; m < 4; ++m) { accz[nf][m] = zf; accx[nf][m] = zf; }

  f16x8 Bz[4];
#pragma unroll
  for (int nf = 0; nf < 4; ++nf)
    Bz[nf] = *(const f16x8*)(a.wz + (size_t)kg*4096 + wlo + nf*512);

#pragma unroll 1
  for (int u = kg; u < 75; u += 4) {
    int tap = u/3, kc = u - tap*3;
    int ky = tap/5, kx = tap - ky*5;
    bool inner = ((unsigned)(ky-1) <= 2u) && ((unsigned)(kx-1) <= 2u);

    f16x8 Bx[4];
    if (inner) {
      int xu = ((ky-1)*3 + (kx-1))*3 + kc;
#pragma unroll
      for (int nf = 0; nf < 4; ++nf)
        Bx[nf] = *(const f16x8*)(a.wx + (size_t)xu*4096 + wlo + nf*512);
    }

    int ai0 = (kc*4 + q)*145 + (row_in + ky)*12 + col + kx;
    f16x8 Ah[4];
#pragma unroll
    for (int m = 0; m < 4; ++m)
      Ah[m] = *(const f16x8*)(AU4 + ai0 + m*24);

#pragma unroll
    for (int nf = 0; nf < 4; ++nf)
#pragma unroll
      for (int m = 0; m < 4; ++m)
        accz[nf][m] = __builtin_amdgcn_mfma_f32_16x16x32_f16(Ah[m], Bz[nf], accz[nf][m], 0,0,0);

    // prefetch next z-B (depth-1, hides L2 latency)
    int un = (u + 4 < 75) ? u + 4 : kg;
    f16x8 Bzn[4];
#pragma unroll
    for (int nf = 0; nf < 4; ++nf)
      Bzn[nf] = *(const f16x8*)(a.wz + (size_t)un*4096 + wlo + nf*512);

    if (inner) {
#pragma unroll
      for (int nf = 0; nf < 4; ++nf)
#pragma unroll
        for (int m = 0; m < 4; ++m)
          accx[nf][m] = __builtin_amdgcn_mfma_f32_16x16x32_f16(Ah[m], Bx[nf], accx[nf][m], 0,0,0);
    }
#pragma unroll
    for (int nf = 0; nf < 4; ++nf) Bz[nf] = Bzn[nf];
  }

  // ---- phase 2: K-reduce (4-way) fused with gating, 4 passes ----
  for (int pass = 0; pass < 4; ++pass) {
    const int br = pass >> 1, mh = pass & 1;       // br0=z, br1=x; Mfrags {2mh,2mh+1}
    __syncthreads();                               // exch free (halo dead / prev pass read)
#pragma unroll
    for (int nf = 0; nf < 4; ++nf)
#pragma unroll
      for (int ml = 0; ml < 2; ++ml) {
        int m = mh*2 + ml;
        exch[((((kg*2 + n)*4 + nf)*2 + ml)*64) + lane] = br ? accx[nf][m] : accz[nf][m];
      }
    __syncthreads();
    if (tid < 256) {
      int ch = tid & 31, pxq = tid >> 5;           // 8 px-quads x 32 channels
      int ml = pxq >> 2, qq = pxq & 3;
      const float* bias = br ? a.bx : a.bz;
      float gsum[4][4];                            // [gate][r]
#pragma unroll
      for (int g = 0; g < 4; ++g) {
        int co = g*32 + ch;
        int nn = co >> 6, nf = (co >> 4) & 3, nl = co & 15;
        int li = qq*16 + nl;
        f32x4 s = zf;
#pragma unroll
        for (int kgg = 0; kgg < 4; ++kgg)
          s += exch[((((kgg*2 + nn)*4 + nf)*2 + ml)*64) + li];
        float bb = bias[co];
#pragma unroll
        for (int r = 0; r < 4; ++r) gsum[g][r] = s[r] + bb;
      }
#pragma unroll
      for (int r = 0; r < 4; ++r) {
        int p16 = qq*4 + r;
        int m = mh*2 + ml;
        int px = (2*m + (p16 >> 3))*8 + (p16 & 7);
        int pxg = (R0 + (px >> 3))*64 + C0 + (px & 7);
        size_t pix = (size_t)b*4096 + pxg;
        float ig = gsum[0][r], fg = gsum[1][r], gg = gsum[2][r], og = gsum[3][r];
        if (br == 0) {                             // z-branch
          float c = a.cz[pix*32 + ch];
          float cn = sigm(fg + 0.01f)*c + sigm(ig)*tanhf(gg);
          float h = sigm(og)*tanhf(cn);
          a.cz[pix*32 + ch] = cn;
          if (a.hz) put_pair(a.hz, b, 64 + ch, pxg, h);
          hbufF[px*68 + 32 + ch] = h;
        } else {                                   // x-branch
          float c = a.cx_src[pix*32 + ch];
          float cn = sigm(fg + 0.01f)*c + sigm(ig)*tanhf(gg);
          float h = sigm(og)*tanhf(cn);
          if (a.cx_dst) a.cx_dst[pix*32 + ch] = cn;
          if (a.hx0) put_pair(a.hx0, b, 32 + ch, pxg, h);
          if (a.hx1) put_pair(a.hx1, b, 32 + ch, pxg, h);
          hbufF[px*68 + ch] = h;
        }
      }
    }
  }
  __syncthreads();

  // ---- phase 3: fused 1x1 y-conv (64 -> 32) ----
  if (a.wy) {
#pragma unroll 1
    for (int it = 0; it < 4; ++it) {
      int idx = tid + it*512;
      int co2 = idx & 31, px = idx >> 5;
      int pxg = (R0 + (px >> 3))*64 + C0 + (px & 7);
      float acc = a.by[co2];
#pragma unroll
      for (int c2 = 0; c2 < 64; ++c2) acc += a.wy[co2*64 + c2] * hbufF[px*68 + c2];
      if (a.y_dst) put_pair(a.y_dst, b, co2, pxg, acc);
      if (a.wl) ybufF[px*37 + co2] = acc;
    }
  }
  // ---- phase 4: fused pred-conv (32 -> 1), last cell only ----
  if (a.wl) {
    __syncthreads();
    if (tid < 64) {
      int px = tid;
      int pxg = (R0 + (px >> 3))*64 + C0 + (px & 7);
      float p = 0.f;
#pragma unroll
      for (int c2 = 0; c2 < 32; ++c2) p += a.wl[c2] * ybufF[px*37 + c2];
      a.pred_out[(size_t)b*4096 + pxg] = p;
      if (a.final_out) a.final_out[(size_t)b*40960 + pxg] = p;
    }
  }
}

extern "C" void kernel_launch(void* const* d_in, const int* in_sizes, int n_in,
                              void* d_out, int out_size, void* d_ws, size_t ws_size,
                              hipStream_t stream)
{
  const float* input_seq = (const float*)d_in[0];
  const float* w_x0 = (const float*)d_in[1];
  const float* b_x0 = (const float*)d_in[2];
  const float* w_z0 = (const float*)d_in[3];
  const float* b_z0 = (const float*)d_in[4];
  const float* w_y0 = (const float*)d_in[5];
  const float* b_y0 = (const float*)d_in[6];
  const float* w_x1 = (const float*)d_in[7];
  const float* b_x1 = (const float*)d_in[8];
  const float* w_z1 = (const float*)d_in[9];
  const float* b_z1 = (const float*)d_in[10];
  const float* w_y1 = (const float*)d_in[11];
  const float* b_y1 = (const float*)d_in[12];
  const float* w_last = (const float*)d_in[13];
  (void)in_sizes; (void)n_in; (void)out_size; (void)ws_size;

  uint8_t* wsb = (uint8_t*)d_ws;
  size_t off = 0;
  auto alloc = [&](size_t bytes) -> void* {
    void* p = wsb + off; off += (bytes + 255) & ~(size_t)255; return p;
  };

  const size_t CATB = (size_t)NB*24*4096*8*2;    // 6,291,456 B (chunk-planar f16)
  u16* cat[3][3][2];
  for (int l = 0; l < 3; ++l)
    for (int s = 0; s < 3; ++s) {
      cat[l][s][0] = (u16*)alloc(CATB);
      cat[l][s][1] = (s == 0) ? (u16*)alloc(CATB) : cat[l][s][0];
    }
  const size_t CB = (size_t)NB*HW*32*4;          // 2,097,152 B
  float* cx[3][2]; float* cz[3];
  for (int l = 0; l < 3; ++l) { cx[l][0] = (float*)alloc(CB); cx[l][1] = (float*)alloc(CB); }
  for (int l = 0; l < 3; ++l) cz[l] = (float*)alloc(CB);
  size_t zero_bytes = off;                       // cats + cx + cz

  u16 *wzb[9], *wxb[9];
  for (int c = 0; c < 9; ++c) {
    wzb[c] = (u16*)alloc(75*4096*2);             // 25 taps x 3 kc x 128 co x 32 k
    wxb[c] = (u16*)alloc(27*4096*2);             // 9 taps x 3 kc
  }
  float* predbuf = (float*)alloc((size_t)18*NB*HW*4);

  zero4<<<2048, 256, 0, stream>>>((uint4*)wsb, zero_bytes/16);

  for (int l = 0; l < 3; ++l)
    for (int s = 0; s < 3; ++s) {
      int cell = l*3 + s;
      const float *srcx, *srcz; int cin;
      if (l == 0) { srcx = w_x0 + (size_t)s*128*65*9;  srcz = w_z0 + (size_t)s*128*65*25;  cin = 65; }
      else { int li = (l-1)*3 + s;
             srcx = w_x1 + (size_t)li*128*96*9; srcz = w_z1 + (size_t)li*128*96*25; cin = 96; }
      pack_w<<<(75*4096)/256, 256, 0, stream>>>(srcz, wzb[cell], 25, cin, l==0);
      pack_w<<<(27*4096)/256, 256, 0, stream>>>(srcx, wxb[cell], 9, cin, l==0);
    }

  for (int step = 0; step < 18; ++step) {
    int par = step & 1, npar = par ^ 1;
    frame_fill<<<dim3(64,3), 256, 0, stream>>>(input_seq, predbuf, step,
        cat[0][0][par], cat[0][1][0], cat[0][2][0]);
    for (int l = 0; l < 3; ++l)
      for (int s = 0; s < 3; ++s) {
        int cell = l*3 + s;
        CellArgs A;
        A.cat_in = cat[l][s][(s==0) ? par : 0];
        A.wz = wzb[cell]; A.wx = wxb[cell];
        if (l == 0) { A.bx = b_x0 + s*128; A.bz = b_z0 + s*128; }
        else { int li = (l-1)*3 + s; A.bx = b_x1 + li*128; A.bz = b_z1 + li*128; }
        A.cx_src = (s == 2) ? cx[l][1] : cx[l][0];
        A.cx_dst = (s == 0) ? cx[l][0] : ((s == 1) ? cx[l][1] : nullptr);
        A.cz = cz[l];
        A.hx0 = (s == 0) ? cat[l][1][0] : ((s == 1) ? cat[l][2][0] : nullptr);
        A.hx1 = (s == 0) ? cat[l][0][npar] : nullptr;
        A.hz  = (s < 2) ? cat[l][s+1][0] : cat[l][0][npar];
        A.wy = nullptr; A.by = nullptr; A.y_dst = nullptr;
        A.wl = nullptr; A.pred_out = nullptr; A.final_out = nullptr;
        if (l < 2) {
          if (l == 0) { A.wy = w_y0 + (size_t)s*32*64; A.by = b_y0 + s*32; }
          else        { A.wy = w_y1 + (size_t)s*32*64; A.by = b_y1 + s*32; }
          A.y_dst = cat[l+1][s][(s==0) ? par : 0];
        } else if (s == 2) {
          A.wy = w_y1 + (size_t)5*32*64; A.by = b_y1 + 5*32;
          A.wl = w_last;
          A.pred_out = predbuf + (size_t)step*NB*HW;
          A.final_out = (step >= 8) ? ((float*)d_out + (size_t)(step-8)*HW) : nullptr;
        }
        cell_kernel<<<dim3(64, NB), 512, 0, stream>>>(A);
      }
  }
}

// Round 4
// 4974.529 us; speedup vs baseline: 1.9937x; 1.0440x over previous
//
#include <hip/hip_runtime.h>
#include <cstddef>
#include <cstdint>

// CubicRNN MI355X — round 8: r7 + dead lo-plane accesses removed. Phase 0
// stages only the 12 live (hi) chunk-planes; put_hi stores only the hi half.
// All remaining global accesses keep their r4/r7 byte addresses: CATB stays
// 6.29 MB with the lo half as dead padding (r5/r6 showed the traffic
// explosion is triggered by re-based buffer geometry, so bases are pinned).
// Numerics bit-identical to r4..r7 (absmax 3.72529e-09).
// B=4, T=10, C=1, H=W=64, HC=32, S=3, L=3, kx=3, kz=5, ky=1, 18 steps.

typedef __attribute__((ext_vector_type(8))) _Float16 f16x8;
typedef __attribute__((ext_vector_type(4))) float f32x4;
typedef unsigned short u16;

#define HW 4096
#define NB 4

__device__ __forceinline__ float sigm(float x){ return 1.f/(1.f+expf(-x)); }
__device__ __forceinline__ u16 f2h(float x){
  _Float16 h = (_Float16)x;
  union { _Float16 f; u16 u; } c; c.f = h; return c.u;
}

__global__ __launch_bounds__(256) void zero4(uint4* __restrict__ p, size_t n){
  size_t i = (size_t)blockIdx.x*blockDim.x + threadIdx.x;
  size_t st = (size_t)gridDim.x*blockDim.x;
  uint4 z = make_uint4(0u,0u,0u,0u);
  for (; i < n; i += st) p[i] = z;
}

// Pack conv weights (fp32 OIHW) -> [unit=tap*3+kc][co(128)][k(32)] f16 single,
// cat channels remapped to uniform 96 (layer0: ci0->k0, ci1..64->k32..95).
__global__ __launch_bounds__(256) void pack_w(const float* __restrict__ src,
    u16* __restrict__ dst, int taps, int cin, int l0){
  int idx = blockIdx.x*256 + threadIdx.x;
  int k = idx & 31, co = (idx>>5) & 127, rest = idx >> 12;
  int tap = rest/3, kc = rest - tap*3;
  int p = kc*32 + k;
  int ci = l0 ? ((p==0) ? 0 : ((p>=32) ? p-31 : -1)) : p;
  float wv = 0.f;
  if (ci >= 0 && ci < cin) wv = src[((size_t)co*cin + ci)*taps + tap];
  dst[idx] = f2h(wv);
}

// cat layout: [b][chunk 0..23][pixel 0..4095][elem 0..7] f16; only chunks
// 0..11 (hi) are live. chunk = slot>>3, elem = slot&7 (slot 0..95).
// Chunks 12..23 are dead padding (address-geometry pinned to r4).
__device__ __forceinline__ void put_hi(u16* base, int b, int slot, int pix, float v){
  size_t o = ((size_t)(b*24 + (slot>>3))*4096 + pix)*8 + (slot&7);
  base[o] = f2h(v);
}

// Write frame (or fed-back pred) into slot 0 of layer-0 cat bufs.
__global__ __launch_bounds__(256) void frame_fill(const float* __restrict__ inseq,
    const float* __restrict__ predbuf, int step,
    u16* __restrict__ c0, u16* __restrict__ c1, u16* __restrict__ c2){
  int s = blockIdx.y;
  u16* dst = (s==0) ? c0 : ((s==1) ? c1 : c2);
  int i = blockIdx.x*256 + threadIdx.x;          // b*4096 + px
  int b = i >> 12, px = i & 4095;
  int j = step + s;
  float v = (j < 10) ? inseq[((size_t)b*10 + j)*HW + px]
                     : predbuf[(size_t)(j-3)*(NB*HW) + (size_t)b*HW + px];
  put_hi(dst, b, 0, px, v);
}

struct CellArgs {
  const u16* cat_in;                       // chunk-planar f16 (12 live chunks)
  const u16* wz; const u16* wx;            // packed f16 weights
  const float *bx, *bz;                    // [128]
  const float* cx_src; float* cx_dst;      // [B][4096][32] fp32 (dst may be null)
  float* cz;                               // in-place
  u16 *hx0, *hx1, *hz, *y_dst;             // cat base pointers (null = skip)
  const float *wy, *by;                    // [32][64],[32]
  const float *wl;                         // [32]; non-null = pred mode
  float *pred_out;                         // predbuf slot [B][4096]
  float *final_out;                        // d_out + ti*4096 (b-stride 40960) or null
};

// LDS: [0,27840) halo (12 chunk-planes x 145 uint4); overlay after K-loop:
//   exch f32x4 [0,65536) ; hbuf f32 [65536, 82944) [64px][68] ;
//   ybuf f32 [82944, 92416) [64px][37]
#define LDS_BYTES 92416

__global__ __launch_bounds__(512, 2) void cell_kernel(CellArgs a){
  __shared__ __align__(16) char smem[LDS_BYTES];
  uint4* AU4   = (uint4*)smem;
  f32x4* exch  = (f32x4*)smem;             // 4096 entries = 64 KB
  float* hbufF = (float*)(smem + 65536);
  float* ybufF = (float*)(smem + 82944);

  const int tid = threadIdx.x;
  const int b = blockIdx.y;
  const int reg = blockIdx.x;
  const int R0 = (reg >> 3) << 3, C0 = (reg & 7) << 3;   // 8x8 pixel region

  // ---- phase 0: stage 12x12 halo, 12 live chunk-planes, coalesced ----
  for (int i = tid; i < 1728; i += 512) {
    int px = i % 144, cp = i / 144;
    int hr = px / 12, hc = px - hr*12;
    int gy = R0 + hr - 2, gx = C0 + hc - 2;
    uint4 v = make_uint4(0u,0u,0u,0u);
    if (gy >= 0 && gy < 64 && gx >= 0 && gx < 64)
      v = *reinterpret_cast<const uint4*>(a.cat_in + ((size_t)(b*24 + cp)*4096 + gy*64 + gx)*8);
    AU4[cp*145 + px] = v;
  }
  __syncthreads();

  // ---- phase 1: K-loop, Ng=2 (64 co/wave) x Kg=4; hi-half MFMAs only ----
  const int wave = tid >> 6, lane = tid & 63;
  const int n = wave & 1, kg = wave >> 1;
  const int q = lane >> 4, n16 = lane & 15;
  const int row_in = n16 >> 3, col = n16 & 7;
  const int cb = n*64;
  const int wlo = (cb + n16)*32 + q*8;     // lane weight offset (nf adds 512)

  f32x4 zf = {0.f,0.f,0.f,0.f};
  f32x4 accz[4][4], accx[4][4];            // [nf][m]
#pragma unroll
  for (int nf = 0; nf < 4; ++nf)
#pragma unroll
    for (int m = 0; m < 4; ++m) { accz[nf][m] = zf; accx[nf][m] = zf; }

  f16x8 Bz[4];
#pragma unroll
  for (int nf = 0; nf < 4; ++nf)
    Bz[nf] = *(const f16x8*)(a.wz + (size_t)kg*4096 + wlo + nf*512);

#pragma unroll 1
  for (int u = kg; u < 75; u += 4) {
    int tap = u/3, kc = u - tap*3;
    int ky = tap/5, kx = tap - ky*5;
    bool inner = ((unsigned)(ky-1) <= 2u) && ((unsigned)(kx-1) <= 2u);

    f16x8 Bx[4];
    if (inner) {
      int xu = ((ky-1)*3 + (kx-1))*3 + kc;
#pragma unroll
      for (int nf = 0; nf < 4; ++nf)
        Bx[nf] = *(const f16x8*)(a.wx + (size_t)xu*4096 + wlo + nf*512);
    }

    int ai0 = (kc*4 + q)*145 + (row_in + ky)*12 + col + kx;
    f16x8 Ah[4];
#pragma unroll
    for (int m = 0; m < 4; ++m)
      Ah[m] = *(const f16x8*)(AU4 + ai0 + m*24);

#pragma unroll
    for (int nf = 0; nf < 4; ++nf)
#pragma unroll
      for (int m = 0; m < 4; ++m)
        accz[nf][m] = __builtin_amdgcn_mfma_f32_16x16x32_f16(Ah[m], Bz[nf], accz[nf][m], 0,0,0);

    // prefetch next z-B (depth-1, hides L2 latency)
    int un = (u + 4 < 75) ? u + 4 : kg;
    f16x8 Bzn[4];
#pragma unroll
    for (int nf = 0; nf < 4; ++nf)
      Bzn[nf] = *(const f16x8*)(a.wz + (size_t)un*4096 + wlo + nf*512);

    if (inner) {
#pragma unroll
      for (int nf = 0; nf < 4; ++nf)
#pragma unroll
        for (int m = 0; m < 4; ++m)
          accx[nf][m] = __builtin_amdgcn_mfma_f32_16x16x32_f16(Ah[m], Bx[nf], accx[nf][m], 0,0,0);
    }
#pragma unroll
    for (int nf = 0; nf < 4; ++nf) Bz[nf] = Bzn[nf];
  }

  // ---- phase 2: K-reduce (4-way) fused with gating, 4 passes ----
  for (int pass = 0; pass < 4; ++pass) {
    const int br = pass >> 1, mh = pass & 1;       // br0=z, br1=x; Mfrags {2mh,2mh+1}
    __syncthreads();                               // exch free (halo dead / prev pass read)
#pragma unroll
    for (int nf = 0; nf < 4; ++nf)
#pragma unroll
      for (int ml = 0; ml < 2; ++ml) {
        int m = mh*2 + ml;
        exch[((((kg*2 + n)*4 + nf)*2 + ml)*64) + lane] = br ? accx[nf][m] : accz[nf][m];
      }
    __syncthreads();
    if (tid < 256) {
      int ch = tid & 31, pxq = tid >> 5;           // 8 px-quads x 32 channels
      int ml = pxq >> 2, qq = pxq & 3;
      const float* bias = br ? a.bx : a.bz;
      float gsum[4][4];                            // [gate][r]
#pragma unroll
      for (int g = 0; g < 4; ++g) {
        int co = g*32 + ch;
        int nn = co >> 6, nf = (co >> 4) & 3, nl = co & 15;
        int li = qq*16 + nl;
        f32x4 s = zf;
#pragma unroll
        for (int kgg = 0; kgg < 4; ++kgg)
          s += exch[((((kgg*2 + nn)*4 + nf)*2 + ml)*64) + li];
        float bb = bias[co];
#pragma unroll
        for (int r = 0; r < 4; ++r) gsum[g][r] = s[r] + bb;
      }
#pragma unroll
      for (int r = 0; r < 4; ++r) {
        int p16 = qq*4 + r;
        int m = mh*2 + ml;
        int px = (2*m + (p16 >> 3))*8 + (p16 & 7);
        int pxg = (R0 + (px >> 3))*64 + C0 + (px & 7);
        size_t pix = (size_t)b*4096 + pxg;
        float ig = gsum[0][r], fg = gsum[1][r], gg = gsum[2][r], og = gsum[3][r];
        if (br == 0) {                             // z-branch
          float c = a.cz[pix*32 + ch];
          float cn = sigm(fg + 0.01f)*c + sigm(ig)*tanhf(gg);
          float h = sigm(og)*tanhf(cn);
          a.cz[pix*32 + ch] = cn;
          if (a.hz) put_hi(a.hz, b, 64 + ch, pxg, h);
          hbufF[px*68 + 32 + ch] = h;
        } else {                                   // x-branch
          float c = a.cx_src[pix*32 + ch];
          float cn = sigm(fg + 0.01f)*c + sigm(ig)*tanhf(gg);
          float h = sigm(og)*tanhf(cn);
          if (a.cx_dst) a.cx_dst[pix*32 + ch] = cn;
          if (a.hx0) put_hi(a.hx0, b, 32 + ch, pxg, h);
          if (a.hx1) put_hi(a.hx1, b, 32 + ch, pxg, h);
          hbufF[px*68 + ch] = h;
        }
      }
    }
  }
  __syncthreads();

  // ---- phase 3: fused 1x1 y-conv (64 -> 32) ----
  if (a.wy) {
#pragma unroll 1
    for (int it = 0; it < 4; ++it) {
      int idx = tid + it*512;
      int co2 = idx & 31, px = idx >> 5;
      int pxg = (R0 + (px >> 3))*64 + C0 + (px & 7);
      float acc = a.by[co2];
#pragma unroll
      for (int c2 = 0; c2 < 64; ++c2) acc += a.wy[co2*64 + c2] * hbufF[px*68 + c2];
      if (a.y_dst) put_hi(a.y_dst, b, co2, pxg, acc);
      if (a.wl) ybufF[px*37 + co2] = acc;
    }
  }
  // ---- phase 4: fused pred-conv (32 -> 1), last cell only ----
  if (a.wl) {
    __syncthreads();
    if (tid < 64) {
      int px = tid;
      int pxg = (R0 + (px >> 3))*64 + C0 + (px & 7);
      float p = 0.f;
#pragma unroll
      for (int c2 = 0; c2 < 32; ++c2) p += a.wl[c2] * ybufF[px*37 + c2];
      a.pred_out[(size_t)b*4096 + pxg] = p;
      if (a.final_out) a.final_out[(size_t)b*40960 + pxg] = p;
    }
  }
}

extern "C" void kernel_launch(void* const* d_in, const int* in_sizes, int n_in,
                              void* d_out, int out_size, void* d_ws, size_t ws_size,
                              hipStream_t stream)
{
  const float* input_seq = (const float*)d_in[0];
  const float* w_x0 = (const float*)d_in[1];
  const float* b_x0 = (const float*)d_in[2];
  const float* w_z0 = (const float*)d_in[3];
  const float* b_z0 = (const float*)d_in[4];
  const float* w_y0 = (const float*)d_in[5];
  const float* b_y0 = (const float*)d_in[6];
  const float* w_x1 = (const float*)d_in[7];
  const float* b_x1 = (const float*)d_in[8];
  const float* w_z1 = (const float*)d_in[9];
  const float* b_z1 = (const float*)d_in[10];
  const float* w_y1 = (const float*)d_in[11];
  const float* b_y1 = (const float*)d_in[12];
  const float* w_last = (const float*)d_in[13];
  (void)in_sizes; (void)n_in; (void)out_size; (void)ws_size;

  uint8_t* wsb = (uint8_t*)d_ws;
  size_t off = 0;
  auto alloc = [&](size_t bytes) -> void* {
    void* p = wsb + off; off += (bytes + 255) & ~(size_t)255; return p;
  };

  const size_t CATB = (size_t)NB*24*4096*8*2;    // 6,291,456 B (geometry pinned; lo half dead)
  u16* cat[3][3][2];
  for (int l = 0; l < 3; ++l)
    for (int s = 0; s < 3; ++s) {
      cat[l][s][0] = (u16*)alloc(CATB);
      cat[l][s][1] = (s == 0) ? (u16*)alloc(CATB) : cat[l][s][0];
    }
  const size_t CB = (size_t)NB*HW*32*4;          // 2,097,152 B
  float* cx[3][2]; float* cz[3];
  for (int l = 0; l < 3; ++l) { cx[l][0] = (float*)alloc(CB); cx[l][1] = (float*)alloc(CB); }
  for (int l = 0; l < 3; ++l) cz[l] = (float*)alloc(CB);
  size_t zero_bytes = off;                       // cats + cx + cz

  u16 *wzb[9], *wxb[9];
  for (int c = 0; c < 9; ++c) {
    wzb[c] = (u16*)alloc(75*4096*2);             // 25 taps x 3 kc x 128 co x 32 k
    wxb[c] = (u16*)alloc(27*4096*2);             // 9 taps x 3 kc
  }
  float* predbuf = (float*)alloc((size_t)18*NB*HW*4);

  zero4<<<2048, 256, 0, stream>>>((uint4*)wsb, zero_bytes/16);

  for (int l = 0; l < 3; ++l)
    for (int s = 0; s < 3; ++s) {
      int cell = l*3 + s;
      const float *srcx, *srcz; int cin;
      if (l == 0) { srcx = w_x0 + (size_t)s*128*65*9;  srcz = w_z0 + (size_t)s*128*65*25;  cin = 65; }
      else { int li = (l-1)*3 + s;
             srcx = w_x1 + (size_t)li*128*96*9; srcz = w_z1 + (size_t)li*128*96*25; cin = 96; }
      pack_w<<<(75*4096)/256, 256, 0, stream>>>(srcz, wzb[cell], 25, cin, l==0);
      pack_w<<<(27*4096)/256, 256, 0, stream>>>(srcx, wxb[cell], 9, cin, l==0);
    }

  for (int step = 0; step < 18; ++step) {
    int par = step & 1, npar = par ^ 1;
    frame_fill<<<dim3(64,3), 256, 0, stream>>>(input_seq, predbuf, step,
        cat[0][0][par], cat[0][1][0], cat[0][2][0]);
    for (int l = 0; l < 3; ++l)
      for (int s = 0; s < 3; ++s) {
        int cell = l*3 + s;
        CellArgs A;
        A.cat_in = cat[l][s][(s==0) ? par : 0];
        A.wz = wzb[cell]; A.wx = wxb[cell];
        if (l == 0) { A.bx = b_x0 + s*128; A.bz = b_z0 + s*128; }
        else { int li = (l-1)*3 + s; A.bx = b_x1 + li*128; A.bz = b_z1 + li*128; }
        A.cx_src = (s == 2) ? cx[l][1] : cx[l][0];
        A.cx_dst = (s == 0) ? cx[l][0] : ((s == 1) ? cx[l][1] : nullptr);
        A.cz = cz[l];
        A.hx0 = (s == 0) ? cat[l][1][0] : ((s == 1) ? cat[l][2][0] : nullptr);
        A.hx1 = (s == 0) ? cat[l][0][npar] : nullptr;
        A.hz  = (s < 2) ? cat[l][s+1][0] : cat[l][0][npar];
        A.wy = nullptr; A.by = nullptr; A.y_dst = nullptr;
        A.wl = nullptr; A.pred_out = nullptr; A.final_out = nullptr;
        if (l < 2) {
          if (l == 0) { A.wy = w_y0 + (size_t)s*32*64; A.by = b_y0 + s*32; }
          else        { A.wy = w_y1 + (size_t)s*32*64; A.by = b_y1 + s*32; }
          A.y_dst = cat[l+1][s][(s==0) ? par : 0];
        } else if (s == 2) {
          A.wy = w_y1 + (size_t)5*32*64; A.by = b_y1 + 5*32;
          A.wl = w_last;
          A.pred_out = predbuf + (size_t)step*NB*HW;
          A.final_out = (step >= 8) ? ((float*)d_out + (size_t)(step-8)*HW) : nullptr;
        }
        cell_kernel<<<dim3(64, NB), 512, 0, stream>>>(A);
      }
  }
}